// Round 3
// baseline (610.669 us; speedup 1.0000x reference)
//
#include <hip/hip_runtime.h>
#include <math.h>

// B=8, N=4096, D=1024, E=512, C=4096.  M = 32768.
// Split-fp16 MFMA emulation of fp32 GEMM (a = h + l/2048, 3 MFMAs) for proj;
// hi-only fp16 pass for sim + deterministic margin rescue (MARGIN=0.03);
// contested rows recomputed exactly.
// R13 = R12 resubmit (R12 bench died with infra-flake signature: 277s npz
// push, truncated traceback; schedule desk-checked 3x) + explicit
// vmcnt(0)/lgkmcnt(0) drain before the epilogue LDS reuse.
// k_sim_h: m201 counted-vmcnt granule schedule:
//   - granules: A alpha(rows {0-63,128-191}, read q0) / beta(+64, q2);
//     B gamma(nh0 rows, q0) / delta(nh1 rows, q1).
//   - per tile T: q0 stages beta(T+1), q1 gamma(T+1), q2 alpha(T+2),
//     q3 delta(T+2); waits ONLY vmcnt(4) at q3 (tile T+1 becomes resident,
//     2 granules stay in flight). Every stage lands >=2 barriers after the
//     slot's last ds_read; never drains to 0 until the last tiles.
//   Fragment reads / swizzle / MFMA mapping / epilogue identical to R11
//   (which passed absmax=0).
// k_gemm1 keeps the R11 XCD chunk swizzle (helped ~25us).
//
// ws (MB): cn_h 0-4, cn_l 4-8, rpT_h 8-9, rpT_l 9-10, proj_h 10-42,
//          proj_l 42-74, pv1 74-78, pi1 78-82, pv2 82-86, rpv 86-90,
//          rpi 90-94, list 94-94.125, cnt @94.125

typedef _Float16 half8 __attribute__((ext_vector_type(8)));
typedef _Float16 half4 __attribute__((ext_vector_type(4)));
typedef float f32x4 __attribute__((ext_vector_type(4)));
typedef unsigned long long u64;
typedef unsigned int u32;

#define INV2048 (4.8828125e-4f)
#define MARGIN 0.03f

struct Split { _Float16 h, l; };

__device__ __forceinline__ Split split_f32(float v) {
    Split s;
    s.h = (_Float16)v;
    s.l = (_Float16)((v - (float)s.h) * 2048.0f);
    return s;
}

__device__ __forceinline__ void gl_lds16(const void* g, void* l) {
    __builtin_amdgcn_global_load_lds(
        (const __attribute__((address_space(1))) unsigned int*)g,
        (__attribute__((address_space(3))) unsigned int*)l, 16, 0, 0);
}

// monotone float->u32 key (finite inputs): order-preserving, key>0
__device__ __forceinline__ u32 fkey(float v) {
    u32 b = __float_as_uint(v);
    return b ^ ((u32)((int)b >> 31) | 0x80000000u);
}
__device__ __forceinline__ float fkeyinv(u32 u) {
    u32 m2 = (u32)((int)u >> 31);
    return __uint_as_float(u ^ ((~m2) | 0x80000000u));
}

// fused: blocks 0..127 transpose+split rp; blocks 128..4223 normalize+split cb
__global__ __launch_bounds__(256) void k_prep(const float* __restrict__ rp,
                                              _Float16* __restrict__ th,
                                              _Float16* __restrict__ tl,
                                              const float* __restrict__ cb,
                                              _Float16* __restrict__ ch,
                                              _Float16* __restrict__ cl,
                                              int* __restrict__ cnt) {
    const int t = threadIdx.x;
    if (blockIdx.x == 0 && t == 0) *cnt = 0;
    if (blockIdx.x < 128) {
        __shared__ float tile[64][65];
        const int k0 = (blockIdx.x & 15) * 64, n0 = (blockIdx.x >> 4) * 64;
        const int rr = t >> 6, cc = t & 63;
        #pragma unroll
        for (int i = 0; i < 16; ++i) {
            int r = i * 4 + rr;
            tile[r][cc] = rp[(size_t)(k0 + r) * 512 + n0 + cc];
        }
        __syncthreads();
        #pragma unroll
        for (int i = 0; i < 16; ++i) {
            int n = i * 4 + rr;
            Split s = split_f32(tile[cc][n]);
            size_t o = (size_t)(n0 + n) * 1024 + k0 + cc;
            th[o] = s.h;
            tl[o] = s.l;
        }
    } else {
        const int c = blockIdx.x - 128;
        const float* row = cb + (size_t)c * 512;
        float v0 = row[t];
        float v1 = row[t + 256];
        float ss = v0 * v0 + v1 * v1;
        #pragma unroll
        for (int o = 32; o > 0; o >>= 1) ss += __shfl_down(ss, o, 64);
        __shared__ float wsum[4];
        if ((t & 63) == 0) wsum[t >> 6] = ss;
        __syncthreads();
        float s = 1.0f / fmaxf(sqrtf(wsum[0] + wsum[1] + wsum[2] + wsum[3]), 1e-12f);
        Split s0 = split_f32(v0 * s);
        ch[(size_t)c * 512 + t] = s0.h;
        cl[(size_t)c * 512 + t] = s0.l;
        Split s1 = split_f32(v1 * s);
        ch[(size_t)c * 512 + t + 256] = s1.h;
        cl[(size_t)c * 512 + t + 256] = s1.l;
    }
}

// proj = x @ rp : M=32768, N=512, K=1024. split-fp16 3-MFMA (accurate).
// 1D grid, XCD chunk swizzle so the 4 nb column-blocks of one mb row-block
// co-reside on one XCD (X rows hit L2, not HBM x4).
__global__ __launch_bounds__(256, 2) void k_gemm1(const float* __restrict__ X,
                                                  const _Float16* __restrict__ Bh,
                                                  const _Float16* __restrict__ Bl,
                                                  _Float16* __restrict__ Ph,
                                                  _Float16* __restrict__ Pl) {
    __shared__ _Float16 sAh[128 * 64], sAl[128 * 64];   // 16 KB each
    __shared__ _Float16 sBh[128 * 64], sBl[128 * 64];   // 16 KB each
    const int t = threadIdx.x;
    const int bid = blockIdx.x;                 // 0..1023
    const int logical = (bid & 7) * 128 + (bid >> 3);   // bijective XCD chunking
    const int nb = logical & 3;   // 0..3
    const int mb = logical >> 2;  // 0..255
    const int lane = t & 63, w = t >> 6;
    const int quad = lane >> 4, l15 = lane & 15;
    const int wm = w >> 1, wn = w & 1;

    f32x4 acc[4][4], acc2[4][4];
    const f32x4 z = {0.f, 0.f, 0.f, 0.f};
    #pragma unroll
    for (int i = 0; i < 4; ++i)
        #pragma unroll
        for (int j = 0; j < 4; ++j) { acc[i][j] = z; acc2[i][j] = z; }

    const int srow8 = lane >> 3;
    const int sseg = (lane & 7) ^ srow8;
    const _Float16* gBh = Bh + (size_t)(nb * 128 + w * 32 + srow8) * 1024 + sseg * 8;
    const _Float16* gBl = Bl + (size_t)(nb * 128 + w * 32 + srow8) * 1024 + sseg * 8;

    const int xrow = t >> 1;
    const int xk8 = (t & 1) * 4;
    const float* gX = X + (size_t)(mb * 128 + xrow) * 1024 + xk8 * 8;
    _Float16* wAh = &sAh[xrow * 64];
    _Float16* wAl = &sAl[xrow * 64];
    const int xswz = xrow & 7;

    for (int ks = 0; ks < 16; ++ks) {
        const int ko = ks * 64;
        __syncthreads();
        #pragma unroll
        for (int c = 0; c < 4; ++c) {
            gl_lds16(gBh + ko + (size_t)(c * 8) * 1024, &sBh[(w * 32 + c * 8) * 64]);
            gl_lds16(gBl + ko + (size_t)(c * 8) * 1024, &sBl[(w * 32 + c * 8) * 64]);
        }
        #pragma unroll
        for (int j = 0; j < 4; ++j) {
            float4 v0 = *(const float4*)(gX + ko + j * 8);
            float4 v1 = *(const float4*)(gX + ko + j * 8 + 4);
            Split s0 = split_f32(v0.x), s1 = split_f32(v0.y);
            Split s2 = split_f32(v0.z), s3 = split_f32(v0.w);
            Split s4 = split_f32(v1.x), s5 = split_f32(v1.y);
            Split s6 = split_f32(v1.z), s7 = split_f32(v1.w);
            half8 hv, lv;
            hv[0] = s0.h; hv[1] = s1.h; hv[2] = s2.h; hv[3] = s3.h;
            hv[4] = s4.h; hv[5] = s5.h; hv[6] = s6.h; hv[7] = s7.h;
            lv[0] = s0.l; lv[1] = s1.l; lv[2] = s2.l; lv[3] = s3.l;
            lv[4] = s4.l; lv[5] = s5.l; lv[6] = s6.l; lv[7] = s7.l;
            const int slot = ((xk8 + j) ^ xswz) * 8;
            *(half8*)&wAh[slot] = hv;
            *(half8*)&wAl[slot] = lv;
        }
        __syncthreads();
        #pragma unroll
        for (int phase = 0; phase < 2; ++phase) {
            const int slot = (((phase << 2) | quad) ^ (l15 & 7)) * 8;
            half8 ah[4], al[4], bh[4], bl[4];
            #pragma unroll
            for (int i = 0; i < 4; ++i) {
                ah[i] = *(const half8*)&sAh[(wm * 64 + i * 16 + l15) * 64 + slot];
                al[i] = *(const half8*)&sAl[(wm * 64 + i * 16 + l15) * 64 + slot];
                bh[i] = *(const half8*)&sBh[(wn * 64 + i * 16 + l15) * 64 + slot];
                bl[i] = *(const half8*)&sBl[(wn * 64 + i * 16 + l15) * 64 + slot];
            }
            #pragma unroll
            for (int mi = 0; mi < 4; ++mi)
                #pragma unroll
                for (int ni = 0; ni < 4; ++ni) {
                    acc[mi][ni]  = __builtin_amdgcn_mfma_f32_16x16x32_f16(ah[mi], bh[ni], acc[mi][ni], 0, 0, 0);
                    acc2[mi][ni] = __builtin_amdgcn_mfma_f32_16x16x32_f16(ah[mi], bl[ni], acc2[mi][ni], 0, 0, 0);
                    acc2[mi][ni] = __builtin_amdgcn_mfma_f32_16x16x32_f16(al[mi], bh[ni], acc2[mi][ni], 0, 0, 0);
                }
        }
    }
    #pragma unroll
    for (int mi = 0; mi < 4; ++mi)
        #pragma unroll
        for (int r = 0; r < 4; ++r) {
            int row = mb * 128 + wm * 64 + mi * 16 + quad * 4 + r;
            #pragma unroll
            for (int ni = 0; ni < 4; ++ni) {
                int col = nb * 128 + wn * 64 + ni * 16 + l15;
                float v = acc[mi][ni][r] + acc2[mi][ni][r] * INV2048;
                Split s = split_f32(v);
                Ph[(size_t)row * 512 + col] = s.h;
                Pl[(size_t)row * 512 + col] = s.l;
            }
        }
}

// ---- k_sim_h phase macros ----------------------------------------------
#define BARX() do { asm volatile("" ::: "memory"); __builtin_amdgcn_s_barrier(); \
                    asm volatile("" ::: "memory"); } while (0)
#define LGKM0() do { asm volatile("s_waitcnt lgkmcnt(0)" ::: "memory"); \
                     __builtin_amdgcn_sched_barrier(0); } while (0)

#define READ_A(MH) do { \
    _Pragma("unroll") \
    for (int ii = 0; ii < 4; ++ii) { \
        _Pragma("unroll") \
        for (int kh = 0; kh < 2; ++kh) \
            a[ii][kh] = *(const half8*)&rA[(wm * 128 + (MH) * 64 + ii * 16 + l15) * 64 \
                                           + ((((kh << 2) | quad) ^ (l15 & 7)) << 3)]; \
    } \
} while (0)

#define READ_B(BS, NH2) do { \
    _Pragma("unroll") \
    for (int jj = 0; jj < 2; ++jj) { \
        _Pragma("unroll") \
        for (int kh = 0; kh < 2; ++kh) \
            BS[jj][kh] = *(const half8*)&rB[(wn * 64 + (NH2) * 32 + jj * 16 + l15) * 64 \
                                            + ((((kh << 2) | quad) ^ (l15 & 7)) << 3)]; \
    } \
} while (0)

#define MFMA_Q(MH, BS, NH2) do { \
    __builtin_amdgcn_s_setprio(1); \
    _Pragma("unroll") \
    for (int ii = 0; ii < 4; ++ii) { \
        _Pragma("unroll") \
        for (int jj = 0; jj < 2; ++jj) { \
            _Pragma("unroll") \
            for (int kh = 0; kh < 2; ++kh) \
                acc[(MH) * 4 + ii][(NH2) * 2 + jj] = \
                    __builtin_amdgcn_mfma_f32_16x16x32_f16(a[ii][kh], BS[jj][kh], \
                        acc[(MH) * 4 + ii][(NH2) * 2 + jj], 0, 0, 0); \
        } \
    } \
    __builtin_amdgcn_s_setprio(0); \
} while (0)

// PASS 1: hi-only sim. 256m x 256c tile, 512 thr (8 waves 2x4), BK=64,
// double-buffered LDS (128 KB), m201 counted-vmcnt granule schedule.
__global__ __launch_bounds__(512, 2) void k_sim_h(const _Float16* __restrict__ Ah,
                                                  const _Float16* __restrict__ Bh,
                                                  float* __restrict__ pv1,
                                                  int* __restrict__ pi1,
                                                  float* __restrict__ pv2) {
    __shared__ __align__(16) _Float16 sA[2][256 * 64];   // 64 KB
    __shared__ __align__(16) _Float16 sB[2][256 * 64];   // 64 KB
    u64* ept = (u64*)&sA[0][0];                          // [256][4] u64 (8 KB)
    u32* epv = (u32*)&sB[0][0];                          // [256][4] u32 (4 KB)
    const int t = threadIdx.x;
    const int cbk = blockIdx.x;  // 0..15 (256-wide c-tiles)
    const int mb = blockIdx.y;   // 0..127 (256-row m-tiles)
    const int lane = t & 63, w = t >> 6;       // 8 waves
    const int quad = lane >> 4, l15 = lane & 15;
    const int wm = w >> 2, wn = w & 3;         // 2 x 4 wave grid

    f32x4 acc[8][4];
    const f32x4 z = {0.f, 0.f, 0.f, 0.f};
    #pragma unroll
    for (int i = 0; i < 8; ++i)
        #pragma unroll
        for (int j = 0; j < 4; ++j) acc[i][j] = z;

    // staging: chunk = 8 rows x 128B, lane ell -> row ell>>3, global seg
    // (ell&7)^(ell>>3). Granule = 128 rows (16 chunks); wave w stages 2.
    const int srow8 = lane >> 3;
    const int sseg = (lane & 7) ^ srow8;

    // A granule g (0=alpha rows {0-63,128-191}, 1=beta +64): wave chunks at
    // r0 = j*128 + g*64 + w*8.  B granule g (0=gamma nh0 rows, 1=delta +32):
    // r0 = (w>>2)*64 + j*128 + g*32 + (w&3)*8.
    auto stageA = [&](int buf, int tile, int g) {
        #pragma unroll
        for (int j = 0; j < 2; ++j) {
            const int r0 = j * 128 + g * 64 + w * 8;
            gl_lds16(Ah + (size_t)(mb * 256 + r0 + srow8) * 512 + tile * 64 + sseg * 8,
                     &sA[buf][r0 * 64]);
        }
    };
    auto stageB = [&](int buf, int tile, int g) {
        #pragma unroll
        for (int j = 0; j < 2; ++j) {
            const int r0 = (w >> 2) * 64 + j * 128 + g * 32 + (w & 3) * 8;
            gl_lds16(Bh + (size_t)(cbk * 256 + r0 + srow8) * 512 + tile * 64 + sseg * 8,
                     &sB[buf][r0 * 64]);
        }
    };

    // prologue: tile 0 complete (alpha,gamma,delta,beta) + alpha,delta of 1
    stageA(0, 0, 0); stageB(0, 0, 0); stageB(0, 0, 1); stageA(0, 0, 1);
    stageA(1, 1, 0); stageB(1, 1, 1);
    asm volatile("s_waitcnt vmcnt(4)" ::: "memory");
    __builtin_amdgcn_s_barrier();
    asm volatile("" ::: "memory");

    half8 a[4][2], bg[2][2], bd[2][2];

    for (int i = 0; i < 4; ++i) {
        #pragma unroll
        for (int h = 0; h < 2; ++h) {
            const int T = 2 * i + h;           // current tile; buf = h
            const _Float16* rA = &sA[h][0];
            const _Float16* rB = &sB[h][0];
            const bool s01 = (T <= 6);         // stage tile T+1 at q0/q1
            const bool s23 = (T <= 5);         // stage tile T+2 at q2/q3

            // q0: (mh0,nh0)   reads a(mh0), bg; stage beta(T+1)
            READ_A(0); READ_B(bg, 0);
            if (s01) stageA(h ^ 1, T + 1, 1);
            BARX(); LGKM0(); MFMA_Q(0, bg, 0); BARX();

            // q1: (mh0,nh1)   reads bd; stage gamma(T+1)
            READ_B(bd, 1);
            if (s01) stageB(h ^ 1, T + 1, 0);
            BARX(); LGKM0(); MFMA_Q(0, bd, 1); BARX();

            // q2: (mh1,nh1)   reads a(mh1); stage alpha(T+2)
            READ_A(1);
            if (s23) stageA(h, T + 2, 0);
            BARX(); LGKM0(); MFMA_Q(1, bd, 1); BARX();

            // q3: (mh1,nh0)   no reads; stage delta(T+2); counted wait
            if (s23) stageB(h, T + 2, 1);
            if (s23)      { asm volatile("s_waitcnt vmcnt(4)" ::: "memory"); }
            else if (s01) { asm volatile("s_waitcnt vmcnt(0)" ::: "memory"); }
            BARX();
            __builtin_amdgcn_sched_barrier(0);
            MFMA_Q(1, bg, 0);
            BARX();
        }
    }

    // drain everything before reusing LDS as the epilogue table
    asm volatile("s_waitcnt vmcnt(0) lgkmcnt(0)" ::: "memory");
    __syncthreads();
    #pragma unroll
    for (int mi = 0; mi < 8; ++mi)
        #pragma unroll
        for (int r = 0; r < 4; ++r) {
            // in-lane top-2 over 4 ni columns
            u64 p1 = 0, p2 = 0;
            #pragma unroll
            for (int ni = 0; ni < 4; ++ni) {
                float v = acc[mi][ni][r];
                u32 col = cbk * 256 + wn * 64 + ni * 16 + l15;
                u64 p = ((u64)fkey(v) << 32) | (u32)(~col);
                if (p > p1) { p2 = p1; p1 = p; }
                else if (p > p2) p2 = p;
            }
            // merge top-2 across the 16 lanes of this row group
            #pragma unroll
            for (int m = 1; m < 16; m <<= 1) {
                u64 q1 = __shfl_xor(p1, m, 64);
                u64 q2 = __shfl_xor(p2, m, 64);
                u64 lo = p1 < q1 ? p1 : q1;
                p1 = p1 < q1 ? q1 : p1;
                p2 = p2 < q2 ? q2 : p2;
                p2 = p2 < lo ? lo : p2;
            }
            if (l15 == 0) {
                int rloc = wm * 128 + mi * 16 + quad * 4 + r;
                ept[rloc * 4 + wn] = p1;
                epv[rloc * 4 + wn] = (u32)(p2 >> 32);
            }
        }
    __syncthreads();
    if (t < 256) {
        u64 b1 = 0, b2 = 0;
        u32 vk2 = 0;
        #pragma unroll
        for (int j = 0; j < 4; ++j) {
            u64 p = ept[t * 4 + j];
            if (p > b1) { b2 = b1; b1 = p; }
            else if (p > b2) b2 = p;
            u32 vk = epv[t * 4 + j];
            vk2 = vk > vk2 ? vk : vk2;
        }
        u32 k2 = (u32)(b2 >> 32);
        if (vk2 > k2) k2 = vk2;
        size_t o = (size_t)(mb * 256 + t) * 16 + cbk;
        pv1[o] = fkeyinv((u32)(b1 >> 32));
        pi1[o] = (int)(~(u32)b1);
        pv2[o] = fkeyinv(k2);
    }
}

// reduce 16 c-tile partials; commit confident rows, queue contested ones
__global__ __launch_bounds__(256) void k_flag(const float* __restrict__ pv1,
                                              const int* __restrict__ pi1,
                                              const float* __restrict__ pv2,
                                              int* __restrict__ out,
                                              int* __restrict__ list,
                                              int* __restrict__ cnt) {
    int r = blockIdx.x * 256 + threadIdx.x;
    if (r >= 32768) return;
    size_t base = (size_t)r * 16;
    float v1 = pv1[base], v2 = pv2[base];
    int i1 = pi1[base];
    #pragma unroll
    for (int j = 1; j < 16; ++j) {
        float ov1 = pv1[base + j], ov2 = pv2[base + j];
        int oi1 = pi1[base + j];
        if (ov1 > v1 || (ov1 == v1 && oi1 < i1)) { v2 = fmaxf(v1, ov2); v1 = ov1; i1 = oi1; }
        else v2 = fmaxf(v2, ov1);
    }
    out[r] = i1;
    if (v1 - v2 < MARGIN) {
        int p = atomicAdd(cnt, 1);
        list[p] = r;
    }
}

// PASS 2: exact 3-MFMA sim on gathered contested rows
__global__ __launch_bounds__(256, 2) void k_sim_fix(const _Float16* __restrict__ Ah,
                                                    const _Float16* __restrict__ Al,
                                                    const _Float16* __restrict__ Bh,
                                                    const _Float16* __restrict__ Bl,
                                                    const int* __restrict__ list,
                                                    const int* __restrict__ cnt,
                                                    float* __restrict__ rpv,
                                                    int* __restrict__ rpi) {
    __shared__ _Float16 sAh[128 * 32], sAl[128 * 32], sBh[128 * 32], sBl[128 * 32];
    __shared__ int rowidx[128];
    __shared__ float pvs[128][2];
    __shared__ int   pis[128][2];
    const int count = *cnt;
    const int t = threadIdx.x;
    const int cbk = blockIdx.x;  // 0..31
    const int lane = t & 63, w = t >> 6;
    const int quad = lane >> 4, l15 = lane & 15;
    const int wm = w >> 1, wn = w & 1;

    const int srow = w * 32 + (lane >> 2);
    const int kcol = (lane & 3) * 8;
    const _Float16* gBh = Bh + (size_t)(cbk * 128 + srow) * 512 + kcol;
    const _Float16* gBl = Bl + (size_t)(cbk * 128 + srow) * 512 + kcol;

    for (int g = blockIdx.y; g * 128 < count; g += gridDim.y) {
        __syncthreads();
        if (t < 128) {
            int p = g * 128 + t;
            rowidx[t] = (p < count) ? list[p] : list[0];
        }
        __syncthreads();

        f32x4 acc[4][4], acc2[4][4];
        const f32x4 z = {0.f, 0.f, 0.f, 0.f};
        #pragma unroll
        for (int i = 0; i < 4; ++i)
            #pragma unroll
            for (int j = 0; j < 4; ++j) { acc[i][j] = z; acc2[i][j] = z; }

        for (int ks = 0; ks < 16; ++ks) {
            const int ko = ks * 32;
            __syncthreads();
            gl_lds16(gBh + ko, &sBh[w * 1024]);
            gl_lds16(gBh + ko + (size_t)16 * 512, &sBh[w * 1024 + 512]);
            gl_lds16(gBl + ko, &sBl[w * 1024]);
            gl_lds16(gBl + ko + (size_t)16 * 512, &sBl[w * 1024 + 512]);
            #pragma unroll
            for (int i = 0; i < 2; ++i) {
                int idx = i * 256 + t;          // 0..511
                int row = idx >> 2, seg = (idx & 3) * 8;
                size_t src = (size_t)rowidx[row] * 512 + ko + seg;
                *(half8*)&sAh[row * 32 + seg] = *(const half8*)(Ah + src);
                *(half8*)&sAl[row * 32 + seg] = *(const half8*)(Al + src);
            }
            __syncthreads();
            half8 ah[4], al[4], bh[4], bl[4];
            #pragma unroll
            for (int i = 0; i < 4; ++i) {
                ah[i] = *(const half8*)&sAh[(wm * 64 + i * 16 + l15) * 32 + quad * 8];
                al[i] = *(const half8*)&sAl[(wm * 64 + i * 16 + l15) * 32 + quad * 8];
                bh[i] = *(const half8*)&sBh[(wn * 64 + i * 16 + l15) * 32 + quad * 8];
                bl[i] = *(const half8*)&sBl[(wn * 64 + i * 16 + l15) * 32 + quad * 8];
            }
            #pragma unroll
            for (int mi = 0; mi < 4; ++mi)
                #pragma unroll
                for (int ni = 0; ni < 4; ++ni) {
                    acc[mi][ni]  = __builtin_amdgcn_mfma_f32_16x16x32_f16(ah[mi], bh[ni], acc[mi][ni], 0, 0, 0);
                    acc2[mi][ni] = __builtin_amdgcn_mfma_f32_16x16x32_f16(ah[mi], bl[ni], acc2[mi][ni], 0, 0, 0);
                    acc2[mi][ni] = __builtin_amdgcn_mfma_f32_16x16x32_f16(al[mi], bh[ni], acc2[mi][ni], 0, 0, 0);
                }
        }

        #pragma unroll
        for (int mi = 0; mi < 4; ++mi)
            #pragma unroll
            for (int r = 0; r < 4; ++r) {
                float bv = -INFINITY;
                int bi = 0x7fffffff;
                #pragma unroll
                for (int ni = 0; ni < 4; ++ni) {
                    float v = acc[mi][ni][r] + acc2[mi][ni][r] * INV2048;
                    int col = cbk * 128 + wn * 64 + ni * 16 + l15;
                    if (v > bv || (v == bv && col < bi)) { bv = v; bi = col; }
                }
                #pragma unroll
                for (int o = 1; o < 16; o <<= 1) {
                    float ov = __shfl_xor(bv, o, 64);
                    int oi = __shfl_xor(bi, o, 64);
                    if (ov > bv || (ov == bv && oi < bi)) { bv = ov; bi = oi; }
                }
                if (l15 == 0) {
                    int row = wm * 64 + mi * 16 + quad * 4 + r;
                    pvs[row][wn] = bv; pis[row][wn] = bi;
                }
            }
        __syncthreads();
        if (t < 128 && g * 128 + t < count) {
            float v0 = pvs[t][0], v1 = pvs[t][1];
            int i0 = pis[t][0], i1 = pis[t][1];
            bool sw = (v1 > v0) || (v1 == v0 && i1 < i0);
            size_t o = (size_t)(g * 128 + t) * 32 + cbk;
            rpv[o] = sw ? v1 : v0;
            rpi[o] = sw ? i1 : i0;
        }
    }
}

__global__ __launch_bounds__(256) void k_fix(const float* __restrict__ rpv,
                                             const int* __restrict__ rpi,
                                             const int* __restrict__ list,
                                             const int* __restrict__ cnt,
                                             int* __restrict__ out) {
    int p = blockIdx.x * 256 + threadIdx.x;
    if (p >= *cnt) return;
    size_t base = (size_t)p * 32;
    float bv = -INFINITY;
    int bi = 0x7fffffff;
    #pragma unroll
    for (int j = 0; j < 32; ++j) {
        float v = rpv[base + j];
        int ci = rpi[base + j];
        if (v > bv || (v == bv && ci < bi)) { bv = v; bi = ci; }
    }
    out[list[p]] = bi;
}

extern "C" void kernel_launch(void* const* d_in, const int* in_sizes, int n_in,
                              void* d_out, int out_size, void* d_ws, size_t ws_size,
                              hipStream_t stream) {
    const float* x  = (const float*)d_in[0];   // [8,4096,1024]
    const float* rp = (const float*)d_in[1];   // [1024,512]
    const float* cb = (const float*)d_in[2];   // [4096,512]
    int* out = (int*)d_out;                    // [32768] int32

    char* ws = (char*)d_ws;
    _Float16* cn_h   = (_Float16*)(ws);
    _Float16* cn_l   = (_Float16*)(ws + ((size_t)4 << 20));
    _Float16* rpT_h  = (_Float16*)(ws + ((size_t)8 << 20));
    _Float16* rpT_l  = (_Float16*)(ws + ((size_t)9 << 20));
    _Float16* proj_h = (_Float16*)(ws + ((size_t)10 << 20));
    _Float16* proj_l = (_Float16*)(ws + ((size_t)42 << 20));
    float*    pv1    = (float*)   (ws + ((size_t)74 << 20));
    int*      pi1    = (int*)     (ws + ((size_t)78 << 20));
    float*    pv2    = (float*)   (ws + ((size_t)82 << 20));
    float*    rpv    = (float*)   (ws + ((size_t)86 << 20));
    int*      rpi    = (int*)     (ws + ((size_t)90 << 20));
    int*      list   = (int*)     (ws + ((size_t)94 << 20));
    int*      cnt    = (int*)     (ws + ((size_t)94 << 20) + (128 << 10));

    k_prep<<<4224, 256, 0, stream>>>(rp, rpT_h, rpT_l, cb, cn_h, cn_l, cnt);
    k_gemm1<<<1024, 256, 0, stream>>>(x, rpT_h, rpT_l, proj_h, proj_l);
    k_sim_h<<<dim3(16, 128), 512, 0, stream>>>(proj_h, cn_h, pv1, pi1, pv2);
    k_flag<<<128, 256, 0, stream>>>(pv1, pi1, pv2, out, list, cnt);
    k_sim_fix<<<dim3(32, 32), 256, 0, stream>>>(proj_h, proj_l, cn_h, cn_l, list, cnt, rpv, rpi);
    k_fix<<<128, 256, 0, stream>>>(rpv, rpi, list, cnt, out);
}

// Round 4
// 549.946 us; speedup vs baseline: 1.1104x; 1.1104x over previous
//
#include <hip/hip_runtime.h>
#include <math.h>

// B=8, N=4096, D=1024, E=512, C=4096.  M = 32768.
// Split-fp16 MFMA emulation of fp32 GEMM (a = h + l/2048, 3 MFMAs) for proj;
// hi-only fp16 pass for sim + deterministic margin rescue (MARGIN=0.03 >
// worst-case 2^-10*||p||*||c|| + eps); contested rows recomputed exactly.
// R14: REVERT k_sim_h to the proven R10 structure (128m x 256c tile, 256 thr,
//      BK=64, single-buffered 48KB LDS, 2 blocks/CU => cross-block MFMA/LDS
//      overlap; 170us, 36% MfmaUtil). The 256^2 8-phase ports (R11/R13) both
//      landed at 23% MfmaUtil/263us: with 128KB LDS -> 1 block/CU, the
//      phase-lockstep LDS bursts (24KB/wave/K-tile vs ~85B/cyc ceiling)
//      serialize against MFMA with nothing to hide them. KEEP the R11
//      k_gemm1 1D-grid XCD chunk swizzle (~25us win, verified 3 rounds).
//
// ws (MB): cn_h 0-4, cn_l 4-8, rpT_h 8-9, rpT_l 9-10, proj_h 10-42,
//          proj_l 42-74, pv1 74-78, pi1 78-82, pv2 82-86, rpv 86-90,
//          rpi 90-94, list 94-94.125, cnt @94.125

typedef _Float16 half8 __attribute__((ext_vector_type(8)));
typedef _Float16 half4 __attribute__((ext_vector_type(4)));
typedef float f32x4 __attribute__((ext_vector_type(4)));
typedef unsigned long long u64;
typedef unsigned int u32;

#define INV2048 (4.8828125e-4f)
#define MARGIN 0.03f

struct Split { _Float16 h, l; };

__device__ __forceinline__ Split split_f32(float v) {
    Split s;
    s.h = (_Float16)v;
    s.l = (_Float16)((v - (float)s.h) * 2048.0f);
    return s;
}

__device__ __forceinline__ void gl_lds16(const void* g, void* l) {
    __builtin_amdgcn_global_load_lds(
        (const __attribute__((address_space(1))) unsigned int*)g,
        (__attribute__((address_space(3))) unsigned int*)l, 16, 0, 0);
}

// monotone float->u32 key (finite inputs): order-preserving, key>0
__device__ __forceinline__ u32 fkey(float v) {
    u32 b = __float_as_uint(v);
    return b ^ ((u32)((int)b >> 31) | 0x80000000u);
}
__device__ __forceinline__ float fkeyinv(u32 u) {
    u32 m2 = (u32)((int)u >> 31);
    return __uint_as_float(u ^ ((~m2) | 0x80000000u));
}

// fused: blocks 0..127 transpose+split rp; blocks 128..4223 normalize+split cb
__global__ __launch_bounds__(256) void k_prep(const float* __restrict__ rp,
                                              _Float16* __restrict__ th,
                                              _Float16* __restrict__ tl,
                                              const float* __restrict__ cb,
                                              _Float16* __restrict__ ch,
                                              _Float16* __restrict__ cl,
                                              int* __restrict__ cnt) {
    const int t = threadIdx.x;
    if (blockIdx.x == 0 && t == 0) *cnt = 0;
    if (blockIdx.x < 128) {
        __shared__ float tile[64][65];
        const int k0 = (blockIdx.x & 15) * 64, n0 = (blockIdx.x >> 4) * 64;
        const int rr = t >> 6, cc = t & 63;
        #pragma unroll
        for (int i = 0; i < 16; ++i) {
            int r = i * 4 + rr;
            tile[r][cc] = rp[(size_t)(k0 + r) * 512 + n0 + cc];
        }
        __syncthreads();
        #pragma unroll
        for (int i = 0; i < 16; ++i) {
            int n = i * 4 + rr;
            Split s = split_f32(tile[cc][n]);
            size_t o = (size_t)(n0 + n) * 1024 + k0 + cc;
            th[o] = s.h;
            tl[o] = s.l;
        }
    } else {
        const int c = blockIdx.x - 128;
        const float* row = cb + (size_t)c * 512;
        float v0 = row[t];
        float v1 = row[t + 256];
        float ss = v0 * v0 + v1 * v1;
        #pragma unroll
        for (int o = 32; o > 0; o >>= 1) ss += __shfl_down(ss, o, 64);
        __shared__ float wsum[4];
        if ((t & 63) == 0) wsum[t >> 6] = ss;
        __syncthreads();
        float s = 1.0f / fmaxf(sqrtf(wsum[0] + wsum[1] + wsum[2] + wsum[3]), 1e-12f);
        Split s0 = split_f32(v0 * s);
        ch[(size_t)c * 512 + t] = s0.h;
        cl[(size_t)c * 512 + t] = s0.l;
        Split s1 = split_f32(v1 * s);
        ch[(size_t)c * 512 + t + 256] = s1.h;
        cl[(size_t)c * 512 + t + 256] = s1.l;
    }
}

// proj = x @ rp : M=32768, N=512, K=1024. split-fp16 3-MFMA (accurate).
// 1D grid, XCD chunk swizzle so the 4 nb column-blocks of one mb row-block
// co-reside on one XCD (X rows hit L2, not HBM x4).
__global__ __launch_bounds__(256, 2) void k_gemm1(const float* __restrict__ X,
                                                  const _Float16* __restrict__ Bh,
                                                  const _Float16* __restrict__ Bl,
                                                  _Float16* __restrict__ Ph,
                                                  _Float16* __restrict__ Pl) {
    __shared__ _Float16 sAh[128 * 64], sAl[128 * 64];   // 16 KB each
    __shared__ _Float16 sBh[128 * 64], sBl[128 * 64];   // 16 KB each
    const int t = threadIdx.x;
    const int bid = blockIdx.x;                 // 0..1023
    const int logical = (bid & 7) * 128 + (bid >> 3);   // bijective XCD chunking
    const int nb = logical & 3;   // 0..3
    const int mb = logical >> 2;  // 0..255
    const int lane = t & 63, w = t >> 6;
    const int quad = lane >> 4, l15 = lane & 15;
    const int wm = w >> 1, wn = w & 1;

    f32x4 acc[4][4], acc2[4][4];
    const f32x4 z = {0.f, 0.f, 0.f, 0.f};
    #pragma unroll
    for (int i = 0; i < 4; ++i)
        #pragma unroll
        for (int j = 0; j < 4; ++j) { acc[i][j] = z; acc2[i][j] = z; }

    // B staging (gl_lds): chunk = 8 rows x 128B; lane ell -> row ell>>3,
    // global seg (ell&7)^(ell>>3). Wave stages 32 rows (4 chunks) of h and l.
    const int srow8 = lane >> 3;
    const int sseg = (lane & 7) ^ srow8;
    const _Float16* gBh = Bh + (size_t)(nb * 128 + w * 32 + srow8) * 1024 + sseg * 8;
    const _Float16* gBl = Bl + (size_t)(nb * 128 + w * 32 + srow8) * 1024 + sseg * 8;

    // X staging (VALU): thread t -> row t>>1, k8 slots (t&1)*4 + j (j=0..3);
    // each slot = 8 fp32 (2 float4) -> half8 h + half8 l at slot^(row&7).
    const int xrow = t >> 1;
    const int xk8 = (t & 1) * 4;
    const float* gX = X + (size_t)(mb * 128 + xrow) * 1024 + xk8 * 8;
    _Float16* wAh = &sAh[xrow * 64];
    _Float16* wAl = &sAl[xrow * 64];
    const int xswz = xrow & 7;

    for (int ks = 0; ks < 16; ++ks) {
        const int ko = ks * 64;
        __syncthreads();
        #pragma unroll
        for (int c = 0; c < 4; ++c) {
            gl_lds16(gBh + ko + (size_t)(c * 8) * 1024, &sBh[(w * 32 + c * 8) * 64]);
            gl_lds16(gBl + ko + (size_t)(c * 8) * 1024, &sBl[(w * 32 + c * 8) * 64]);
        }
        #pragma unroll
        for (int j = 0; j < 4; ++j) {
            float4 v0 = *(const float4*)(gX + ko + j * 8);
            float4 v1 = *(const float4*)(gX + ko + j * 8 + 4);
            Split s0 = split_f32(v0.x), s1 = split_f32(v0.y);
            Split s2 = split_f32(v0.z), s3 = split_f32(v0.w);
            Split s4 = split_f32(v1.x), s5 = split_f32(v1.y);
            Split s6 = split_f32(v1.z), s7 = split_f32(v1.w);
            half8 hv, lv;
            hv[0] = s0.h; hv[1] = s1.h; hv[2] = s2.h; hv[3] = s3.h;
            hv[4] = s4.h; hv[5] = s5.h; hv[6] = s6.h; hv[7] = s7.h;
            lv[0] = s0.l; lv[1] = s1.l; lv[2] = s2.l; lv[3] = s3.l;
            lv[4] = s4.l; lv[5] = s5.l; lv[6] = s6.l; lv[7] = s7.l;
            const int slot = ((xk8 + j) ^ xswz) * 8;
            *(half8*)&wAh[slot] = hv;
            *(half8*)&wAl[slot] = lv;
        }
        __syncthreads();
        #pragma unroll
        for (int phase = 0; phase < 2; ++phase) {
            const int slot = (((phase << 2) | quad) ^ (l15 & 7)) * 8;
            half8 ah[4], al[4], bh[4], bl[4];
            #pragma unroll
            for (int i = 0; i < 4; ++i) {
                ah[i] = *(const half8*)&sAh[(wm * 64 + i * 16 + l15) * 64 + slot];
                al[i] = *(const half8*)&sAl[(wm * 64 + i * 16 + l15) * 64 + slot];
                bh[i] = *(const half8*)&sBh[(wn * 64 + i * 16 + l15) * 64 + slot];
                bl[i] = *(const half8*)&sBl[(wn * 64 + i * 16 + l15) * 64 + slot];
            }
            #pragma unroll
            for (int mi = 0; mi < 4; ++mi)
                #pragma unroll
                for (int ni = 0; ni < 4; ++ni) {
                    acc[mi][ni]  = __builtin_amdgcn_mfma_f32_16x16x32_f16(ah[mi], bh[ni], acc[mi][ni], 0, 0, 0);
                    acc2[mi][ni] = __builtin_amdgcn_mfma_f32_16x16x32_f16(ah[mi], bl[ni], acc2[mi][ni], 0, 0, 0);
                    acc2[mi][ni] = __builtin_amdgcn_mfma_f32_16x16x32_f16(al[mi], bh[ni], acc2[mi][ni], 0, 0, 0);
                }
        }
    }
    #pragma unroll
    for (int mi = 0; mi < 4; ++mi)
        #pragma unroll
        for (int r = 0; r < 4; ++r) {
            int row = mb * 128 + wm * 64 + mi * 16 + quad * 4 + r;
            #pragma unroll
            for (int ni = 0; ni < 4; ++ni) {
                int col = nb * 128 + wn * 64 + ni * 16 + l15;
                float v = acc[mi][ni][r] + acc2[mi][ni][r] * INV2048;
                Split s = split_f32(v);
                Ph[(size_t)row * 512 + col] = s.h;
                Pl[(size_t)row * 512 + col] = s.l;
            }
        }
}

// PASS 1: hi-only sim. 128m x 256c tile, BK=64, 8 K-iters, 2 barriers/iter.
// Swizzle: LDS slot s (16B units, 8/row) of row r holds global seg s^(r&7).
__global__ __launch_bounds__(256, 2) void k_sim_h(const _Float16* __restrict__ Ah,
                                                  const _Float16* __restrict__ Bh,
                                                  float* __restrict__ pv1,
                                                  int* __restrict__ pi1,
                                                  float* __restrict__ pv2) {
    __shared__ __align__(16) long long smem64[6144];   // 48 KB
    _Float16* sA = (_Float16*)smem64;                  // [128][64] halfs, 16 KB
    _Float16* sB = sA + 128 * 64;                      // [256][64] halfs, 32 KB
    u64* ept = (u64*)smem64;                           // [128][32] u64, 32 KB
    u32* epv = (u32*)((char*)smem64 + 32768);          // [128][32] u32, 16 KB
    const int t = threadIdx.x;
    const int cbk = blockIdx.x;  // 0..15 (256-wide c-tiles)
    const int mb = blockIdx.y;   // 0..255
    const int lane = t & 63, w = t >> 6;
    const int quad = lane >> 4, l15 = lane & 15;
    const int wm = w >> 1, wn = w & 1;

    f32x4 acc[4][8];
    const f32x4 z = {0.f, 0.f, 0.f, 0.f};
    #pragma unroll
    for (int i = 0; i < 4; ++i)
        #pragma unroll
        for (int j = 0; j < 8; ++j) acc[i][j] = z;

    const int srow8 = lane >> 3;
    const int sseg = (lane & 7) ^ srow8;
    const _Float16* gA = Ah + (size_t)(mb * 128 + w * 32 + srow8) * 512 + sseg * 8;
    const _Float16* gB = Bh + (size_t)(cbk * 256 + w * 64 + srow8) * 512 + sseg * 8;

    for (int ks = 0; ks < 8; ++ks) {
        const int ko = ks * 64;
        __syncthreads();
        #pragma unroll
        for (int c = 0; c < 4; ++c)
            gl_lds16(gA + ko + (size_t)(c * 8) * 512, &sA[(w * 32 + c * 8) * 64]);
        #pragma unroll
        for (int c = 0; c < 8; ++c)
            gl_lds16(gB + ko + (size_t)(c * 8) * 512, &sB[(w * 64 + c * 8) * 64]);
        __syncthreads();
        #pragma unroll
        for (int phase = 0; phase < 2; ++phase) {
            const int slot = (((phase << 2) | quad) ^ (l15 & 7)) * 8;
            half8 a[4], b[8];
            #pragma unroll
            for (int i = 0; i < 4; ++i)
                a[i] = *(const half8*)&sA[(wm * 64 + i * 16 + l15) * 64 + slot];
            #pragma unroll
            for (int j = 0; j < 8; ++j)
                b[j] = *(const half8*)&sB[(wn * 128 + j * 16 + l15) * 64 + slot];
            #pragma unroll
            for (int mi = 0; mi < 4; ++mi)
                #pragma unroll
                for (int ni = 0; ni < 8; ++ni)
                    acc[mi][ni] = __builtin_amdgcn_mfma_f32_16x16x32_f16(a[mi], b[ni], acc[mi][ni], 0, 0, 0);
        }
    }

    __syncthreads();   // staging dead; reuse LDS as epilogue table
    #pragma unroll
    for (int mi = 0; mi < 4; ++mi)
        #pragma unroll
        for (int r = 0; r < 4; ++r) {
            int row = wm * 64 + mi * 16 + quad * 4 + r;
            u64 p1 = 0, p2 = 0;
            #pragma unroll
            for (int ni = 0; ni < 8; ++ni) {
                float v = acc[mi][ni][r];
                u32 col = cbk * 256 + wn * 128 + ni * 16 + l15;
                u64 p = ((u64)fkey(v) << 32) | (u32)(~col);
                if (p > p1) { p2 = p1; p1 = p; }
                else if (p > p2) p2 = p;
            }
            int e = row * 32 + wn * 16 + l15;
            ept[e] = p1;
            epv[e] = (u32)(p2 >> 32);
        }
    __syncthreads();
    if (t < 128) {
        u64 b1 = 0, b2 = 0;
        u32 vk2 = 0;
        #pragma unroll
        for (int jj = 0; jj < 32; ++jj) {
            int j = (jj + t) & 31;
            u64 p = ept[t * 32 + j];
            if (p > b1) { b2 = b1; b1 = p; }
            else if (p > b2) b2 = p;
            u32 vk = epv[t * 32 + j];
            vk2 = vk > vk2 ? vk : vk2;
        }
        u32 k2 = (u32)(b2 >> 32);
        if (vk2 > k2) k2 = vk2;
        size_t o = (size_t)(mb * 128 + t) * 16 + cbk;
        pv1[o] = fkeyinv((u32)(b1 >> 32));
        pi1[o] = (int)(~(u32)b1);
        pv2[o] = fkeyinv(k2);
    }
}

// reduce 16 c-tile partials; commit confident rows, queue contested ones
__global__ __launch_bounds__(256) void k_flag(const float* __restrict__ pv1,
                                              const int* __restrict__ pi1,
                                              const float* __restrict__ pv2,
                                              int* __restrict__ out,
                                              int* __restrict__ list,
                                              int* __restrict__ cnt) {
    int r = blockIdx.x * 256 + threadIdx.x;
    if (r >= 32768) return;
    size_t base = (size_t)r * 16;
    float v1 = pv1[base], v2 = pv2[base];
    int i1 = pi1[base];
    #pragma unroll
    for (int j = 1; j < 16; ++j) {
        float ov1 = pv1[base + j], ov2 = pv2[base + j];
        int oi1 = pi1[base + j];
        if (ov1 > v1 || (ov1 == v1 && oi1 < i1)) { v2 = fmaxf(v1, ov2); v1 = ov1; i1 = oi1; }
        else v2 = fmaxf(v2, ov1);
    }
    out[r] = i1;
    if (v1 - v2 < MARGIN) {
        int p = atomicAdd(cnt, 1);
        list[p] = r;
    }
}

// PASS 2: exact 3-MFMA sim on gathered contested rows
__global__ __launch_bounds__(256, 2) void k_sim_fix(const _Float16* __restrict__ Ah,
                                                    const _Float16* __restrict__ Al,
                                                    const _Float16* __restrict__ Bh,
                                                    const _Float16* __restrict__ Bl,
                                                    const int* __restrict__ list,
                                                    const int* __restrict__ cnt,
                                                    float* __restrict__ rpv,
                                                    int* __restrict__ rpi) {
    __shared__ _Float16 sAh[128 * 32], sAl[128 * 32], sBh[128 * 32], sBl[128 * 32];
    __shared__ int rowidx[128];
    __shared__ float pvs[128][2];
    __shared__ int   pis[128][2];
    const int count = *cnt;
    const int t = threadIdx.x;
    const int cbk = blockIdx.x;  // 0..31
    const int lane = t & 63, w = t >> 6;
    const int quad = lane >> 4, l15 = lane & 15;
    const int wm = w >> 1, wn = w & 1;

    const int srow = w * 32 + (lane >> 2);
    const int kcol = (lane & 3) * 8;
    const _Float16* gBh = Bh + (size_t)(cbk * 128 + srow) * 512 + kcol;
    const _Float16* gBl = Bl + (size_t)(cbk * 128 + srow) * 512 + kcol;

    for (int g = blockIdx.y; g * 128 < count; g += gridDim.y) {
        __syncthreads();
        if (t < 128) {
            int p = g * 128 + t;
            rowidx[t] = (p < count) ? list[p] : list[0];
        }
        __syncthreads();

        f32x4 acc[4][4], acc2[4][4];
        const f32x4 z = {0.f, 0.f, 0.f, 0.f};
        #pragma unroll
        for (int i = 0; i < 4; ++i)
            #pragma unroll
            for (int j = 0; j < 4; ++j) { acc[i][j] = z; acc2[i][j] = z; }

        for (int ks = 0; ks < 16; ++ks) {
            const int ko = ks * 32;
            __syncthreads();
            gl_lds16(gBh + ko, &sBh[w * 1024]);
            gl_lds16(gBh + ko + (size_t)16 * 512, &sBh[w * 1024 + 512]);
            gl_lds16(gBl + ko, &sBl[w * 1024]);
            gl_lds16(gBl + ko + (size_t)16 * 512, &sBl[w * 1024 + 512]);
            #pragma unroll
            for (int i = 0; i < 2; ++i) {
                int idx = i * 256 + t;          // 0..511
                int row = idx >> 2, seg = (idx & 3) * 8;
                size_t src = (size_t)rowidx[row] * 512 + ko + seg;
                *(half8*)&sAh[row * 32 + seg] = *(const half8*)(Ah + src);
                *(half8*)&sAl[row * 32 + seg] = *(const half8*)(Al + src);
            }
            __syncthreads();
            half8 ah[4], al[4], bh[4], bl[4];
            #pragma unroll
            for (int i = 0; i < 4; ++i) {
                ah[i] = *(const half8*)&sAh[(wm * 64 + i * 16 + l15) * 32 + quad * 8];
                al[i] = *(const half8*)&sAl[(wm * 64 + i * 16 + l15) * 32 + quad * 8];
                bh[i] = *(const half8*)&sBh[(wn * 64 + i * 16 + l15) * 32 + quad * 8];
                bl[i] = *(const half8*)&sBl[(wn * 64 + i * 16 + l15) * 32 + quad * 8];
            }
            #pragma unroll
            for (int mi = 0; mi < 4; ++mi)
                #pragma unroll
                for (int ni = 0; ni < 4; ++ni) {
                    acc[mi][ni]  = __builtin_amdgcn_mfma_f32_16x16x32_f16(ah[mi], bh[ni], acc[mi][ni], 0, 0, 0);
                    acc2[mi][ni] = __builtin_amdgcn_mfma_f32_16x16x32_f16(ah[mi], bl[ni], acc2[mi][ni], 0, 0, 0);
                    acc2[mi][ni] = __builtin_amdgcn_mfma_f32_16x16x32_f16(al[mi], bh[ni], acc2[mi][ni], 0, 0, 0);
                }
        }

        #pragma unroll
        for (int mi = 0; mi < 4; ++mi)
            #pragma unroll
            for (int r = 0; r < 4; ++r) {
                float bv = -INFINITY;
                int bi = 0x7fffffff;
                #pragma unroll
                for (int ni = 0; ni < 4; ++ni) {
                    float v = acc[mi][ni][r] + acc2[mi][ni][r] * INV2048;
                    int col = cbk * 128 + wn * 64 + ni * 16 + l15;
                    if (v > bv || (v == bv && col < bi)) { bv = v; bi = col; }
                }
                #pragma unroll
                for (int o = 1; o < 16; o <<= 1) {
                    float ov = __shfl_xor(bv, o, 64);
                    int oi = __shfl_xor(bi, o, 64);
                    if (ov > bv || (ov == bv && oi < bi)) { bv = ov; bi = oi; }
                }
                if (l15 == 0) {
                    int row = wm * 64 + mi * 16 + quad * 4 + r;
                    pvs[row][wn] = bv; pis[row][wn] = bi;
                }
            }
        __syncthreads();
        if (t < 128 && g * 128 + t < count) {
            float v0 = pvs[t][0], v1 = pvs[t][1];
            int i0 = pis[t][0], i1 = pis[t][1];
            bool sw = (v1 > v0) || (v1 == v0 && i1 < i0);
            size_t o = (size_t)(g * 128 + t) * 32 + cbk;
            rpv[o] = sw ? v1 : v0;
            rpi[o] = sw ? i1 : i0;
        }
    }
}

__global__ __launch_bounds__(256) void k_fix(const float* __restrict__ rpv,
                                             const int* __restrict__ rpi,
                                             const int* __restrict__ list,
                                             const int* __restrict__ cnt,
                                             int* __restrict__ out) {
    int p = blockIdx.x * 256 + threadIdx.x;
    if (p >= *cnt) return;
    size_t base = (size_t)p * 32;
    float bv = -INFINITY;
    int bi = 0x7fffffff;
    #pragma unroll
    for (int j = 0; j < 32; ++j) {
        float v = rpv[base + j];
        int ci = rpi[base + j];
        if (v > bv || (v == bv && ci < bi)) { bv = v; bi = ci; }
    }
    out[list[p]] = bi;
}

extern "C" void kernel_launch(void* const* d_in, const int* in_sizes, int n_in,
                              void* d_out, int out_size, void* d_ws, size_t ws_size,
                              hipStream_t stream) {
    const float* x  = (const float*)d_in[0];   // [8,4096,1024]
    const float* rp = (const float*)d_in[1];   // [1024,512]
    const float* cb = (const float*)d_in[2];   // [4096,512]
    int* out = (int*)d_out;                    // [32768] int32

    char* ws = (char*)d_ws;
    _Float16* cn_h   = (_Float16*)(ws);
    _Float16* cn_l   = (_Float16*)(ws + ((size_t)4 << 20));
    _Float16* rpT_h  = (_Float16*)(ws + ((size_t)8 << 20));
    _Float16* rpT_l  = (_Float16*)(ws + ((size_t)9 << 20));
    _Float16* proj_h = (_Float16*)(ws + ((size_t)10 << 20));
    _Float16* proj_l = (_Float16*)(ws + ((size_t)42 << 20));
    float*    pv1    = (float*)   (ws + ((size_t)74 << 20));
    int*      pi1    = (int*)     (ws + ((size_t)78 << 20));
    float*    pv2    = (float*)   (ws + ((size_t)82 << 20));
    float*    rpv    = (float*)   (ws + ((size_t)86 << 20));
    int*      rpi    = (int*)     (ws + ((size_t)90 << 20));
    int*      list   = (int*)     (ws + ((size_t)94 << 20));
    int*      cnt    = (int*)     (ws + ((size_t)94 << 20) + (128 << 10));

    k_prep<<<4224, 256, 0, stream>>>(rp, rpT_h, rpT_l, cb, cn_h, cn_l, cnt);
    k_gemm1<<<1024, 256, 0, stream>>>(x, rpT_h, rpT_l, proj_h, proj_l);
    k_sim_h<<<dim3(16, 256), 256, 0, stream>>>(proj_h, cn_h, pv1, pi1, pv2);
    k_flag<<<128, 256, 0, stream>>>(pv1, pi1, pv2, out, list, cnt);
    k_sim_fix<<<dim3(32, 32), 256, 0, stream>>>(proj_h, proj_l, cn_h, cn_l, list, cnt, rpv, rpi);
    k_fix<<<128, 256, 0, stream>>>(rpv, rpi, list, cnt, out);
}